// Round 3
// baseline (568.395 us; speedup 1.0000x reference)
//
#include <hip/hip_runtime.h>

#define NPTS 32768
#define KK 32
#define DD 32

// ---------------- init: copy inputs into ws state ----------------
__global__ __launch_bounds__(256) void init_kernel(
    const float* __restrict__ means0, const float* __restrict__ cov0,
    const float* __restrict__ w0,
    float* __restrict__ meansA, float* __restrict__ covS, float* __restrict__ wS)
{
    int i = blockIdx.x * 256 + threadIdx.x;
    if (i < 1024)  meansA[i] = means0[i];
    if (i < 32768) covS[i]   = cov0[i];
    if (i < 32)    wS[i]     = w0[i];
}

// ---------------- prep: per-k inverse, det, b = A*mu, c = mu^T A mu, coef ----------------
// A2 layout: [f/2][32 k][2] where f = d*32+e   (for 2-way-free ds_read_b64 in estep)
// b2 layout: [d/2][32 k][2]
__global__ __launch_bounds__(256) void prep_kernel(
    const float* __restrict__ cov, const float* __restrict__ means_in,
    const float* __restrict__ wts,
    float* __restrict__ A2, float* __restrict__ b2,
    float* __restrict__ cvec, float* __restrict__ coef)
{
    int k   = blockIdx.x;
    int tid = threadIdx.x;
    __shared__ float M[32][66];   // cols 0..31 = cov, 32..63 = identity->inverse
    __shared__ float mu[32];
    __shared__ float bb[32];

    for (int i = tid; i < 1024; i += 256) {
        int r = i >> 5, c = i & 31;
        M[r][c]      = cov[k * 1024 + i];
        M[r][32 + c] = (r == c) ? 1.0f : 0.0f;
    }
    if (tid < 32) mu[tid] = means_in[k * 32 + tid];
    __syncthreads();

    int r  = tid >> 3;          // 0..31 (row for elimination)
    int c0 = (tid & 7) * 8;     // 0,8,...,56
    float det = 1.0f;
    for (int s = 0; s < 32; ++s) {
        float piv = M[s][s];
        det *= piv;
        float rp = 1.0f / piv;
        float f  = (r != s) ? M[r][s] : 0.0f;   // pre-elimination col-s value
        __syncthreads();                        // all reads done
        if (tid < 64) M[s][tid] *= rp;          // scale pivot row (64 augmented cols)
        __syncthreads();                        // scaled row visible
        if (r != s) {
            #pragma unroll
            for (int j = 0; j < 8; ++j) M[r][c0 + j] -= f * M[s][c0 + j];
        }
        __syncthreads();
    }

    // write A (= inverse) into transposed float2-friendly layout
    for (int i = tid; i < 1024; i += 256) {
        int d = i >> 5, e = i & 31;
        float val = M[d][32 + e];
        A2[(i >> 1) * 64 + k * 2 + (i & 1)] = val;
    }
    // b = A * mu
    if (tid < 32) {
        int d = tid;
        float bd = 0.0f;
        #pragma unroll
        for (int e = 0; e < 32; ++e) bd += M[d][32 + e] * mu[e];
        bb[d] = bd;
        b2[(d >> 1) * 64 + k * 2 + (d & 1)] = bd;
    }
    __syncthreads();
    if (tid == 0) {
        float cc = 0.0f;
        #pragma unroll
        for (int d = 0; d < 32; ++d) cc += mu[d] * bb[d];
        cvec[k] = cc;
        coef[k] = wts[k] / sqrtf(det);
    }
}

// ---------------- estep: responsibilities P[n][k] ----------------
// block = 1024 threads (16 waves); wave = 2 half-waves x 32 k; each thread: 2 points, 1 k.
__global__ __launch_bounds__(1024) void estep_kernel(
    const float* __restrict__ data, const float* __restrict__ A2g,
    const float* __restrict__ b2g, const float* __restrict__ cvec,
    const float* __restrict__ coefg, float* __restrict__ P)
{
    __shared__ alignas(16) float A2s[32768];   // 128 KiB
    int tid = threadIdx.x;
    // stage A into LDS (same linear layout)
    for (int i = tid; i < 8192; i += 1024)
        ((float4*)A2s)[i] = ((const float4*)A2g)[i];
    __syncthreads();

    int lane = tid & 63;
    int wv   = tid >> 6;        // 0..15
    int k    = lane & 31;
    int g    = lane >> 5;       // half-wave
    int p0   = blockIdx.x * 64 + wv * 4 + g * 2;   // this thread: points p0, p0+1

    float x0[32], x1[32];
    const float4* d0p = (const float4*)(data + (size_t)p0 * 32);
    const float4* d1p = (const float4*)(data + (size_t)(p0 + 1) * 32);
    #pragma unroll
    for (int j = 0; j < 8; ++j) {
        float4 v = d0p[j];
        x0[4*j] = v.x; x0[4*j+1] = v.y; x0[4*j+2] = v.z; x0[4*j+3] = v.w;
        float4 u = d1p[j];
        x1[4*j] = u.x; x1[4*j+1] = u.y; x1[4*j+2] = u.z; x1[4*j+3] = u.w;
    }

    float q0 = 0.0f, q1 = 0.0f;
    #pragma unroll
    for (int d = 0; d < 32; ++d) {
        float r0 = 0.0f, s0 = 0.0f, r1 = 0.0f, s1 = 0.0f;
        #pragma unroll
        for (int c = 0; c < 16; ++c) {
            float2 a = *(const float2*)&A2s[(d * 16 + c) * 64 + (k << 1)];
            r0 += a.x * x0[2*c];     s0 += a.y * x0[2*c + 1];
            r1 += a.x * x1[2*c];     s1 += a.y * x1[2*c + 1];
        }
        q0 += x0[d] * (r0 + s0);
        q1 += x1[d] * (r1 + s1);
    }

    float bx0 = 0.0f, bx1 = 0.0f;
    #pragma unroll
    for (int d2 = 0; d2 < 16; ++d2) {
        float2 b = *(const float2*)&b2g[d2 * 64 + (k << 1)];
        bx0 += b.x * x0[2*d2] + b.y * x0[2*d2 + 1];
        bx1 += b.x * x1[2*d2] + b.y * x1[2*d2 + 1];
    }
    float cc = cvec[k], cf = coefg[k];
    float e0 = cf * __expf(-0.5f * (q0 - 2.0f * bx0 + cc));
    float e1 = cf * __expf(-0.5f * (q1 - 2.0f * bx1 + cc));

    // sum over the 32 k-lanes of each half-wave
    float s0r = e0, s1r = e1;
    #pragma unroll
    for (int m = 16; m >= 1; m >>= 1) {
        s0r += __shfl_xor(s0r, m, 64);
        s1r += __shfl_xor(s1r, m, 64);
    }
    P[(size_t)p0 * 32 + k]       = e0 / s0r;
    P[(size_t)(p0 + 1) * 32 + k] = e1 / s1r;
}

// ---------------- mstep: partial S, m, Nk per (k, chunk) ----------------
// grid = 32 chunks x 32 k; block 256 threads: 2 parity groups x (16 d-pairs x 8 e-quads)
#define PSTRIDE 1060
__global__ __launch_bounds__(256) void mstep_kernel(
    const float* __restrict__ data, const float* __restrict__ P,
    float* __restrict__ partial)
{
    int k     = blockIdx.x & 31;
    int chunk = blockIdx.x >> 5;
    int tid   = threadIdx.x;
    int g     = tid >> 7;      // parity group (0: waves 0-1, 1: waves 2-3)
    int t     = tid & 127;
    int dp    = t >> 3;        // 0..15 -> d0 = 2dp
    int eq    = t & 7;         // e0 = 4eq

    __shared__ alignas(16) float Xf[128 * 32];   // 128-point tile
    __shared__ float Sc[128 * 11];               // combine scratch

    float S00=0,S01=0,S02=0,S03=0,S10=0,S11=0,S12=0,S13=0;
    float m0 = 0.0f, m1 = 0.0f, nk = 0.0f;
    int base = chunk * 1024;

    for (int tile = 0; tile < 8; ++tile) {
        __syncthreads();
        for (int i = tid; i < 1024; i += 256)
            ((float4*)Xf)[i] = ((const float4*)(data + (size_t)(base + tile * 128) * 32))[i];
        __syncthreads();
        int n0 = g * 64;
        for (int n = 0; n < 64; ++n) {
            int gn  = base + tile * 128 + n0 + n;
            float p = P[(size_t)gn * 32 + k];              // wave-uniform -> scalar load
            float2 xd = *(const float2*)&Xf[(n0 + n) * 32 + 2 * dp];
            float4 xe = *(const float4*)&Xf[(n0 + n) * 32 + 4 * eq];
            float px0 = p * xd.x, px1 = p * xd.y;
            S00 += px0 * xe.x; S01 += px0 * xe.y; S02 += px0 * xe.z; S03 += px0 * xe.w;
            S10 += px1 * xe.x; S11 += px1 * xe.y; S12 += px1 * xe.z; S13 += px1 * xe.w;
            m0 += px0; m1 += px1;    // meaningful for eq==0 threads
            nk += p;                 // meaningful for t==0
        }
    }
    __syncthreads();
    if (g == 1) {
        Sc[t*11+0]=S00; Sc[t*11+1]=S01; Sc[t*11+2]=S02; Sc[t*11+3]=S03;
        Sc[t*11+4]=S10; Sc[t*11+5]=S11; Sc[t*11+6]=S12; Sc[t*11+7]=S13;
        Sc[t*11+8]=m0;  Sc[t*11+9]=m1;  Sc[t*11+10]=nk;
    }
    __syncthreads();
    if (g == 0) {
        S00+=Sc[t*11+0]; S01+=Sc[t*11+1]; S02+=Sc[t*11+2]; S03+=Sc[t*11+3];
        S10+=Sc[t*11+4]; S11+=Sc[t*11+5]; S12+=Sc[t*11+6]; S13+=Sc[t*11+7];
        m0 +=Sc[t*11+8]; m1 +=Sc[t*11+9]; nk+=Sc[t*11+10];
        float* out = partial + (size_t)(chunk * 32 + k) * PSTRIDE;
        int d0 = 2 * dp, e0 = 4 * eq;
        out[d0*32 + e0 + 0] = S00; out[d0*32 + e0 + 1] = S01;
        out[d0*32 + e0 + 2] = S02; out[d0*32 + e0 + 3] = S03;
        out[(d0+1)*32 + e0 + 0] = S10; out[(d0+1)*32 + e0 + 1] = S11;
        out[(d0+1)*32 + e0 + 2] = S12; out[(d0+1)*32 + e0 + 3] = S13;
        if (eq == 0) { out[1024 + d0] = m0; out[1024 + d0 + 1] = m1; }
        if (t == 0)  out[1056] = nk;
    }
}

// ---------------- reduce m, Nk; write new means & weights ----------------
__global__ void reduce_mnk_kernel(const float* __restrict__ partial,
    float* __restrict__ Nk, float* __restrict__ mvec,
    float* __restrict__ means_out, float* __restrict__ weights_out)
{
    int k = blockIdx.x, tid = threadIdx.x;
    __shared__ float nksh;
    if (tid == 0) {
        float s = 0.0f;
        for (int ch = 0; ch < 32; ++ch) s += partial[(size_t)(ch * 32 + k) * PSTRIDE + 1056];
        Nk[k] = s; weights_out[k] = s / (float)NPTS; nksh = s;
    }
    __syncthreads();
    if (tid < 32) {
        float s = 0.0f;
        for (int ch = 0; ch < 32; ++ch) s += partial[(size_t)(ch * 32 + k) * PSTRIDE + 1024 + tid];
        mvec[k * 32 + tid] = s;
        means_out[k * 32 + tid] = s / nksh;
    }
}

// ---------------- reduce S; write new covariance (uses OLD means) ----------------
__global__ __launch_bounds__(256) void cov_kernel(const float* __restrict__ partial,
    const float* __restrict__ Nk, const float* __restrict__ mvec,
    const float* __restrict__ means_old, float* __restrict__ cov_state)
{
    int idx = blockIdx.x * 256 + threadIdx.x;   // 0..32767
    int k = idx >> 10, de = idx & 1023, d = de >> 5, e = de & 31;
    float s = 0.0f;
    for (int ch = 0; ch < 32; ++ch) s += partial[(size_t)(ch * 32 + k) * PSTRIDE + de];
    float nk   = Nk[k];
    float mu_d = means_old[k * 32 + d], mu_e = means_old[k * 32 + e];
    float mn_d = mvec[k * 32 + d] / nk, mn_e = mvec[k * 32 + e] / nk;
    cov_state[idx] = s / nk - mu_d * mn_e - mn_d * mu_e + mu_d * mu_e;
}

// ---------------- writeout ----------------
__global__ __launch_bounds__(256) void writeout_kernel(
    const float* __restrict__ means, const float* __restrict__ cov,
    const float* __restrict__ w, float* __restrict__ out)
{
    int i = blockIdx.x * 256 + threadIdx.x;
    if (i < 1024)  out[i] = means[i];
    if (i < 32768) out[1024 + i] = cov[i];
    if (i < 32)    out[33792 + i] = w[i];
}

extern "C" void kernel_launch(void* const* d_in, const int* in_sizes, int n_in,
                              void* d_out, int out_size, void* d_ws, size_t ws_size,
                              hipStream_t stream) {
    (void)in_sizes; (void)n_in; (void)out_size; (void)ws_size;
    const float* data   = (const float*)d_in[0];
    const float* means0 = (const float*)d_in[1];
    const float* cov0   = (const float*)d_in[2];
    const float* w0     = (const float*)d_in[3];

    float* ws      = (float*)d_ws;
    float* A2      = ws + 0;        // 32768
    float* b2      = ws + 32768;    // 1024
    float* cvec    = ws + 33792;    // 32
    float* coef    = ws + 33824;    // 32
    float* meansA  = ws + 33856;    // 1024
    float* meansB  = ws + 34880;    // 1024
    float* covS    = ws + 35904;    // 32768
    float* wS      = ws + 68672;    // 32
    float* Nk      = ws + 68704;    // 32
    float* mvec    = ws + 68736;    // 1024
    float* P       = ws + 69760;    // 32768*32 = 1048576
    float* partial = ws + 1118336;  // 32*32*1060 = 1085440

    init_kernel<<<128, 256, 0, stream>>>(means0, cov0, w0, meansA, covS, wS);
    float* mi = meansA;
    float* mo = meansB;
    for (int it = 0; it < 4; ++it) {
        prep_kernel<<<32, 256, 0, stream>>>(covS, mi, wS, A2, b2, cvec, coef);
        estep_kernel<<<512, 1024, 0, stream>>>(data, A2, b2, cvec, coef, P);
        mstep_kernel<<<1024, 256, 0, stream>>>(data, P, partial);
        reduce_mnk_kernel<<<32, 64, 0, stream>>>(partial, Nk, mvec, mo, wS);
        cov_kernel<<<128, 256, 0, stream>>>(partial, Nk, mvec, mi, covS);
        float* tmp = mi; mi = mo; mo = tmp;
    }
    writeout_kernel<<<128, 256, 0, stream>>>(mi, covS, wS, (float*)d_out);
}

// Round 5
// 500.142 us; speedup vs baseline: 1.1365x; 1.1365x over previous
//
#include <hip/hip_runtime.h>

#define NPTS 32768
#define PREC 1057           // partial record: 1024 S + 32 m + 1 nk

// ---------------- prep: per-k inverse, det, b = A*mu, c = mu^T A mu, coef ----------------
// A2 layout: [f/2][32 k][2] where f = d*32+e ; b2 layout: [d/2][32 k][2]
__global__ __launch_bounds__(256) void prep_kernel(
    const float* __restrict__ cov, const float* __restrict__ means_in,
    const float* __restrict__ wts,
    float* __restrict__ A2, float* __restrict__ b2,
    float* __restrict__ cvec, float* __restrict__ coef)
{
    int k   = blockIdx.x;
    int tid = threadIdx.x;
    __shared__ float M[32][66];
    __shared__ float mu[32];
    __shared__ float bb[32];

    for (int i = tid; i < 1024; i += 256) {
        int r = i >> 5, c = i & 31;
        M[r][c]      = cov[k * 1024 + i];
        M[r][32 + c] = (r == c) ? 1.0f : 0.0f;
    }
    if (tid < 32) mu[tid] = means_in[k * 32 + tid];
    __syncthreads();

    int r  = tid >> 3;
    int c0 = (tid & 7) * 8;
    float det = 1.0f;
    for (int s = 0; s < 32; ++s) {
        float piv = M[s][s];
        det *= piv;
        float rp = 1.0f / piv;
        float f  = (r != s) ? M[r][s] : 0.0f;
        __syncthreads();
        if (tid < 64) M[s][tid] *= rp;
        __syncthreads();
        if (r != s) {
            #pragma unroll
            for (int j = 0; j < 8; ++j) M[r][c0 + j] -= f * M[s][c0 + j];
        }
        __syncthreads();
    }

    for (int i = tid; i < 1024; i += 256) {
        int d = i >> 5, e = i & 31;
        A2[(i >> 1) * 64 + k * 2 + (i & 1)] = M[d][32 + e];
    }
    if (tid < 32) {
        int d = tid;
        float bd = 0.0f;
        #pragma unroll
        for (int e = 0; e < 32; ++e) bd += M[d][32 + e] * mu[e];
        bb[d] = bd;
        b2[(d >> 1) * 64 + k * 2 + (d & 1)] = bd;
    }
    __syncthreads();
    if (tid == 0) {
        float cc = 0.0f;
        #pragma unroll
        for (int d = 0; d < 32; ++d) cc += mu[d] * bb[d];
        cvec[k] = cc;
        coef[k] = wts[k] / sqrtf(det);
    }
}

// ---------------- estep: responsibilities P[n][k] ----------------
// block = 512 threads (8 waves); thread = (k = lane&31, 4 points). 64 pts/block, 512 blocks.
__global__ __launch_bounds__(512, 2) void estep_kernel(
    const float* __restrict__ data, const float* __restrict__ A2g,
    const float* __restrict__ b2g, const float* __restrict__ cvec,
    const float* __restrict__ coefg, float* __restrict__ P)
{
    __shared__ alignas(16) float A2s[32768];   // 128 KiB
    int tid = threadIdx.x;
    for (int i = tid; i < 8192; i += 512)
        ((float4*)A2s)[i] = ((const float4*)A2g)[i];
    __syncthreads();

    int lane = tid & 63;
    int wv   = tid >> 6;        // 0..7
    int k    = lane & 31;
    int g    = lane >> 5;
    int p0   = blockIdx.x * 64 + wv * 8 + g * 4;   // 4 points p0..p0+3

    float x0[32], x1[32], x2[32], x3[32];
    {
        const float4* dp0 = (const float4*)(data + (size_t)p0 * 32);
        const float4* dp1 = (const float4*)(data + (size_t)(p0 + 1) * 32);
        const float4* dp2 = (const float4*)(data + (size_t)(p0 + 2) * 32);
        const float4* dp3 = (const float4*)(data + (size_t)(p0 + 3) * 32);
        #pragma unroll
        for (int j = 0; j < 8; ++j) {
            float4 v0 = dp0[j]; x0[4*j]=v0.x; x0[4*j+1]=v0.y; x0[4*j+2]=v0.z; x0[4*j+3]=v0.w;
            float4 v1 = dp1[j]; x1[4*j]=v1.x; x1[4*j+1]=v1.y; x1[4*j+2]=v1.z; x1[4*j+3]=v1.w;
            float4 v2 = dp2[j]; x2[4*j]=v2.x; x2[4*j+1]=v2.y; x2[4*j+2]=v2.z; x2[4*j+3]=v2.w;
            float4 v3 = dp3[j]; x3[4*j]=v3.x; x3[4*j+1]=v3.y; x3[4*j+2]=v3.z; x3[4*j+3]=v3.w;
        }
    }

    float q0 = 0.0f, q1 = 0.0f, q2 = 0.0f, q3 = 0.0f;
    #pragma unroll
    for (int d = 0; d < 32; ++d) {
        float r0=0, s0=0, r1=0, s1=0, r2=0, s2=0, r3=0, s3=0;
        #pragma unroll
        for (int c = 0; c < 16; ++c) {
            float2 a = *(const float2*)&A2s[(d * 16 + c) * 64 + (k << 1)];
            r0 += a.x * x0[2*c];  s0 += a.y * x0[2*c+1];
            r1 += a.x * x1[2*c];  s1 += a.y * x1[2*c+1];
            r2 += a.x * x2[2*c];  s2 += a.y * x2[2*c+1];
            r3 += a.x * x3[2*c];  s3 += a.y * x3[2*c+1];
        }
        q0 += x0[d] * (r0 + s0);
        q1 += x1[d] * (r1 + s1);
        q2 += x2[d] * (r2 + s2);
        q3 += x3[d] * (r3 + s3);
    }

    float b0=0, b1=0, b2v=0, b3=0;
    #pragma unroll
    for (int d2 = 0; d2 < 16; ++d2) {
        float2 b = *(const float2*)&b2g[d2 * 64 + (k << 1)];
        b0 += b.x * x0[2*d2] + b.y * x0[2*d2+1];
        b1 += b.x * x1[2*d2] + b.y * x1[2*d2+1];
        b2v+= b.x * x2[2*d2] + b.y * x2[2*d2+1];
        b3 += b.x * x3[2*d2] + b.y * x3[2*d2+1];
    }
    float cc = cvec[k], cf = coefg[k];
    float e0 = cf * __expf(-0.5f * (q0 - 2.0f * b0  + cc));
    float e1 = cf * __expf(-0.5f * (q1 - 2.0f * b1  + cc));
    float e2 = cf * __expf(-0.5f * (q2 - 2.0f * b2v + cc));
    float e3 = cf * __expf(-0.5f * (q3 - 2.0f * b3  + cc));

    float t0=e0, t1=e1, t2=e2, t3=e3;
    #pragma unroll
    for (int m = 16; m >= 1; m >>= 1) {
        t0 += __shfl_xor(t0, m, 64);
        t1 += __shfl_xor(t1, m, 64);
        t2 += __shfl_xor(t2, m, 64);
        t3 += __shfl_xor(t3, m, 64);
    }
    P[(size_t)p0 * 32 + k]       = e0 / t0;
    P[(size_t)(p0 + 1) * 32 + k] = e1 / t1;
    P[(size_t)(p0 + 2) * 32 + k] = e2 / t2;
    P[(size_t)(p0 + 3) * 32 + k] = e3 / t3;
}

// ---------------- mstep: partial S (full 32x32), m, Nk per (k, chunk) ----------------
// grid = 32 chunks x 32 k; block 256: tile = tid&31 -> (dt=tile>>2: 4 d's, et=tile&3: 8 e's),
// ng = tid>>5: 8-way n-split. chunk = 1024 pts, staged 256 at a time.
__global__ __launch_bounds__(256, 4) void mstep_kernel(
    const float* __restrict__ data, const float* __restrict__ P,
    float* __restrict__ partial)
{
    int k     = blockIdx.x & 31;
    int chunk = blockIdx.x >> 5;
    int tid   = threadIdx.x;
    int tile  = tid & 31;
    int ng    = tid >> 5;
    int dt    = tile >> 2;   // d0 = 4*dt
    int et    = tile & 3;    // e0 = 8*et

    __shared__ alignas(16) float SH[8 * 1088];   // 34 KB: X-tile (8192) / combine scratch

    float acc[4][8];
    #pragma unroll
    for (int i = 0; i < 4; ++i)
        #pragma unroll
        for (int j = 0; j < 8; ++j) acc[i][j] = 0.0f;
    float m0=0, m1=0, m2=0, m3=0, nk=0;

    int base = chunk * 1024;
    for (int stage = 0; stage < 4; ++stage) {
        __syncthreads();
        for (int i = tid; i < 2048; i += 256)
            ((float4*)SH)[i] = ((const float4*)(data + (size_t)(base + stage * 256) * 32))[i];
        __syncthreads();
        const float4* X4 = (const float4*)SH;
        int nb = ng * 32;
        #pragma unroll 4
        for (int nn = 0; nn < 32; ++nn) {
            int n  = nb + nn;
            float p = P[(size_t)(base + stage * 256 + n) * 32 + k];
            float4 xd  = X4[n * 8 + dt];
            float4 xe0 = X4[n * 8 + et * 2];
            float4 xe1 = X4[n * 8 + et * 2 + 1];
            float p0 = p * xd.x, p1 = p * xd.y, p2 = p * xd.z, p3 = p * xd.w;
            acc[0][0]+=p0*xe0.x; acc[0][1]+=p0*xe0.y; acc[0][2]+=p0*xe0.z; acc[0][3]+=p0*xe0.w;
            acc[0][4]+=p0*xe1.x; acc[0][5]+=p0*xe1.y; acc[0][6]+=p0*xe1.z; acc[0][7]+=p0*xe1.w;
            acc[1][0]+=p1*xe0.x; acc[1][1]+=p1*xe0.y; acc[1][2]+=p1*xe0.z; acc[1][3]+=p1*xe0.w;
            acc[1][4]+=p1*xe1.x; acc[1][5]+=p1*xe1.y; acc[1][6]+=p1*xe1.z; acc[1][7]+=p1*xe1.w;
            acc[2][0]+=p2*xe0.x; acc[2][1]+=p2*xe0.y; acc[2][2]+=p2*xe0.z; acc[2][3]+=p2*xe0.w;
            acc[2][4]+=p2*xe1.x; acc[2][5]+=p2*xe1.y; acc[2][6]+=p2*xe1.z; acc[2][7]+=p2*xe1.w;
            acc[3][0]+=p3*xe0.x; acc[3][1]+=p3*xe0.y; acc[3][2]+=p3*xe0.z; acc[3][3]+=p3*xe0.w;
            acc[3][4]+=p3*xe1.x; acc[3][5]+=p3*xe1.y; acc[3][6]+=p3*xe1.z; acc[3][7]+=p3*xe1.w;
            if (et == 0) { m0 += p0; m1 += p1; m2 += p2; m3 += p3; }
            if (tile == 0) nk += p;
        }
    }
    __syncthreads();   // X region dead; reuse SH as combine scratch

    // write accs, bank-rotated: S entry (d = 4dt+i, e = 8et+j) stored at
    // row d, col (e + dt) & 31  -> 32 distinct banks across the 32 tiles.
    {
        float* Sg = SH + ng * 1088;
        #pragma unroll
        for (int i = 0; i < 4; ++i) {
            int row = dt * 4 + i;
            #pragma unroll
            for (int j = 0; j < 8; ++j) {
                int col = (et * 8 + j + dt) & 31;
                Sg[row * 32 + col] = acc[i][j];
            }
        }
        if (et == 0) {
            Sg[1024 + dt * 4 + 0] = m0; Sg[1024 + dt * 4 + 1] = m1;
            Sg[1024 + dt * 4 + 2] = m2; Sg[1024 + dt * 4 + 3] = m3;
        }
        if (tile == 0) Sg[1056] = nk;
    }
    __syncthreads();

    // reduce over 8 ng and write global partial record (de-rotated)
    float* out = partial + (size_t)(chunk * 32 + k) * PREC;
    for (int e = tid; e < PREC; e += 256) {
        int ridx;
        if (e < 1024) {
            int row = e >> 5, col = e & 31;
            ridx = row * 32 + ((col + (row >> 2)) & 31);
        } else ridx = e;
        float s = 0.0f;
        #pragma unroll
        for (int gg = 0; gg < 8; ++gg) s += SH[gg * 1088 + ridx];
        out[e] = s;
    }
}

// ---------------- finalize: reduce partials; write means/cov/weights (ws + d_out) ----------------
__global__ __launch_bounds__(256) void finalize_kernel(
    const float* __restrict__ partial, const float* __restrict__ means_old,
    float* __restrict__ covS, float* __restrict__ means_new_ws,
    float* __restrict__ wS, float* __restrict__ out)
{
    int k = blockIdx.x, tid = threadIdx.x;
    __shared__ float SS[PREC];
    __shared__ float MU[32];
    __shared__ float MB[32];

    for (int e = tid; e < PREC; e += 256) {
        float s = 0.0f;
        for (int ch = 0; ch < 32; ++ch)
            s += partial[(size_t)(ch * 32 + k) * PREC + e];
        SS[e] = s;
    }
    if (tid < 32) MU[tid] = means_old[k * 32 + tid];
    __syncthreads();

    float nk = SS[1056];
    float rnk = 1.0f / nk;
    if (tid < 32) {
        float mb = SS[1024 + tid] * rnk;
        MB[tid] = mb;
        means_new_ws[k * 32 + tid] = mb;
        out[k * 32 + tid] = mb;
    }
    __syncthreads();

    for (int idx = tid; idx < 1024; idx += 256) {
        int d = idx >> 5, e = idx & 31;
        float c = SS[idx] * rnk - MU[d] * MB[e] - MB[d] * MU[e] + MU[d] * MU[e];
        covS[k * 1024 + idx] = c;
        out[1024 + k * 1024 + idx] = c;
    }
    if (tid == 0) {
        float w = nk * (1.0f / (float)NPTS);
        wS[k] = w;
        out[33792 + k] = w;
    }
}

extern "C" void kernel_launch(void* const* d_in, const int* in_sizes, int n_in,
                              void* d_out, int out_size, void* d_ws, size_t ws_size,
                              hipStream_t stream) {
    (void)in_sizes; (void)n_in; (void)out_size; (void)ws_size;
    const float* data   = (const float*)d_in[0];
    const float* means0 = (const float*)d_in[1];
    const float* cov0   = (const float*)d_in[2];
    const float* w0     = (const float*)d_in[3];

    float* ws      = (float*)d_ws;
    float* A2      = ws + 0;        // 32768
    float* b2      = ws + 32768;    // 1024
    float* cvec    = ws + 33792;    // 32
    float* coef    = ws + 33824;    // 32
    float* meansA  = ws + 33856;    // 1024
    float* meansB  = ws + 34880;    // 1024
    float* covS    = ws + 35904;    // 32768
    float* wS      = ws + 68672;    // 32
    float* P       = ws + 68704;    // 32768*32 = 1048576
    float* partial = ws + 1117280;  // 32*32*1057 = 1082368  (end ~8.8 MB)

    float* mi = meansA;   // means consumed this iter (old)
    float* mo = meansB;   // means produced this iter (new)
    for (int it = 0; it < 4; ++it) {
        const float* cov_src = (it == 0) ? cov0   : covS;
        const float* mns_src = (it == 0) ? means0 : mi;
        const float* w_src   = (it == 0) ? w0     : wS;
        prep_kernel<<<32, 256, 0, stream>>>(cov_src, mns_src, w_src, A2, b2, cvec, coef);
        estep_kernel<<<512, 512, 0, stream>>>(data, A2, b2, cvec, coef, P);
        mstep_kernel<<<1024, 256, 0, stream>>>(data, P, partial);
        finalize_kernel<<<32, 256, 0, stream>>>(partial, mns_src, covS, mo, wS, (float*)d_out);
        float* tmp = mi; mi = mo; mo = tmp;
    }
}